// Round 2
// baseline (148.413 us; speedup 1.0000x reference)
//
#include <hip/hip_runtime.h>
#include <math.h>

#define BLOCK 256

// 16B chunk with only 4B alignment (feature rows are 65 floats = 260B stride).
// LLVM emits global_load_dwordx4 for align-4 global loads on gfx9+.
struct F4a4 { float a, b, c, d; };

__device__ __forceinline__ float exp2_fast(float x) {
#if __has_builtin(__builtin_amdgcn_exp2f)
    return __builtin_amdgcn_exp2f(x);   // bare v_exp_f32
#else
    return __expf(x * 0.69314718055994531f);
#endif
}

__global__ __launch_bounds__(BLOCK) void lbd_kernel(
    const int* __restrict__ uid_in, const int* __restrict__ iid_in,
    const float* __restrict__ uf,  const float* __restrict__ vf,
    const float* __restrict__ ubt, const float* __restrict__ ibt,
    const float* __restrict__ uae, const float* __restrict__ ube,
    const float* __restrict__ iae, const float* __restrict__ ibe,
    const float* __restrict__ gbp, float* __restrict__ out, int B)
{
    __shared__ float2 s_tl[64];          // (t_i, log2 t_i)  -- f32 smooth path
    __shared__ float2 s_ll[64];          // (log2 t_i, log2(1-t_i))
    __shared__ float  s_out[BLOCK * 10];

    const int tid = threadIdx.x;
    if (tid < 64) {
        // f32 t table only feeds the SMOOTH integrand (mask decisions are f64).
        const double step = 1.0 / 63.0;
        float tf = (float)((double)tid * step);
        if (tid == 63) tf = 1.0f;
        float lt = __log2f(tf);
        float l1 = __log2f(1.0f - tf);
        s_tl[tid] = make_float2(tf, lt);
        s_ll[tid] = make_float2(lt, l1);
    }
    __syncthreads();

    const int gid = blockIdx.x * BLOCK + tid;
    float mass[10];
#pragma unroll
    for (int j = 0; j < 10; ++j) mass[j] = 0.0f;

    if (gid < B) {
        const int u = uid_in[gid];
        const int v = iid_in[gid];

        // ---- feature gather + dot/norms (smooth; any summation order) ----
        const float* pu = uf + (long long)u * 65;
        const float* pv = vf + (long long)v * 65;
        float dot = 0.f, su = 0.f, sv = 0.f;
#pragma unroll
        for (int k = 0; k < 16; ++k) {
            F4a4 a = ((const F4a4*)pu)[k];
            F4a4 b = ((const F4a4*)pv)[k];
            dot += a.a * b.a + a.b * b.b + a.c * b.c + a.d * b.d;
            su  += a.a * a.a + a.b * a.b + a.c * a.c + a.d * a.d;
            sv  += b.a * b.a + b.b * b.b + b.c * b.c + b.d * b.d;
        }

        const float gb = gbp[0];
        const float len_prod = sqrtf(su) * sqrtf(sv);
        const float EPS = 1e-6f;
        const float HI  = (float)(1.0 - 1e-6);
        float mu = 0.5f + (0.5f * dot) / fmaxf(len_prod, EPS);
        mu = fminf(fmaxf(mu, EPS), HI);
        const float ups = fmaxf(fabsf(dot), EPS);
        const float al0 = fmaxf(0.01f, mu * ups);
        const float be0 = fmaxf(0.01f, ups - al0);
        const float alpha = fmaxf(0.01f, (gb + al0) + uae[u] + iae[v]);
        const float beta  = fmaxf(0.01f, (gb + be0) + ube[u] + ibe[v]);
        const float am1 = alpha - 1.0f;
        const float bm1 = beta  - 1.0f;

        // ---- bin edges x_j in FULL FLOAT64 (mask-critical chain) ----------
        // In f64, any reasonable exp/sum/div implementation agrees to ~1e-16,
        // so the t_i <= x_j decisions are insensitive to implementation slop.
        const float* pb = ubt + (long long)u * 10;
        const float* qb = ibt + (long long)v * 10;
        double tmd[10];
#pragma unroll
        for (int k = 0; k < 10; ++k)
            tmd[k] = exp((double)pb[k] + (double)qb[k]);
        double ssum = 0.0;
#pragma unroll
        for (int k = 0; k < 10; ++k) ssum = ssum + tmd[k];
        double xs[9];
        {
            double c = 0.0;
#pragma unroll
            for (int j = 0; j < 9; ++j) {
                c = c + tmd[j] / ssum;
                xs[j] = c;
            }
        }

        // ---- denominator B(a,b) trapz (smooth; f32 fast path, 4-acc ILP) --
        float d0 = 0.f, d1 = 0.f, d2 = 0.f, d3 = 0.f;
        {
            int i = 1;                      // i=0 and i=63 terms are exactly 0
            for (; i + 3 <= 62; i += 4) {
                float2 l0 = s_ll[i], l1v = s_ll[i + 1], l2 = s_ll[i + 2], l3 = s_ll[i + 3];
                d0 += exp2_fast(fmaf(am1, l0.x,  bm1 * l0.y));
                d1 += exp2_fast(fmaf(am1, l1v.x, bm1 * l1v.y));
                d2 += exp2_fast(fmaf(am1, l2.x,  bm1 * l2.y));
                d3 += exp2_fast(fmaf(am1, l3.x,  bm1 * l3.y));
            }
            for (; i <= 62; ++i) {
                float2 l0 = s_ll[i];
                d0 += exp2_fast(fmaf(am1, l0.x, bm1 * l0.y));
            }
        }
        const float dtf = (float)(1.0 / 63.0);
        const float Bab = ((d0 + d1) + (d2 + d3)) * dtf;

        // ---- numerators Bx(x_j): mask bound in f64, integrand in f32 ------
        const double STEP = 1.0 / 63.0;
        float cdf[9];
#pragma unroll
        for (int j = 0; j < 9; ++j) {
            const double x  = xs[j];
            const float  xf = (float)x;
            const float  lx = __log2f(xf);
            const float  alx = am1 * lx;
            // imax = largest i with t_i <= x, computed exactly as np f64:
            // t_i = i * (1.0/63.0) rounded per-element, t_63 := 1.0 (x<1 always).
            int im = (int)(x * 63.0);
            if (im > 62) im = 62;
            while (im < 62 && (double)(im + 1) * STEP <= x) ++im;
            while (im >= 1 && (double)im * STEP > x) --im;
            float a0 = 0.f, a1 = 0.f, a2 = 0.f, a3 = 0.f;
            int i = 1;
            for (; i + 3 <= im; i += 4) {
                float2 t0 = s_tl[i], t1 = s_tl[i + 1], t2 = s_tl[i + 2], t3 = s_tl[i + 3];
                a0 += exp2_fast(fmaf(bm1, __log2f(fmaf(-t0.x, xf, 1.0f)), fmaf(am1, t0.y, alx)));
                a1 += exp2_fast(fmaf(bm1, __log2f(fmaf(-t1.x, xf, 1.0f)), fmaf(am1, t1.y, alx)));
                a2 += exp2_fast(fmaf(bm1, __log2f(fmaf(-t2.x, xf, 1.0f)), fmaf(am1, t2.y, alx)));
                a3 += exp2_fast(fmaf(bm1, __log2f(fmaf(-t3.x, xf, 1.0f)), fmaf(am1, t3.y, alx)));
            }
            for (; i <= im; ++i) {
                float2 t0 = s_tl[i];
                a0 += exp2_fast(fmaf(bm1, __log2f(fmaf(-t0.x, xf, 1.0f)), fmaf(am1, t0.y, alx)));
            }
            const float s = (a0 + a1) + (a2 + a3);
            cdf[j] = (s * dtf) / Bab;
        }

        mass[0] = cdf[0];
#pragma unroll
        for (int j = 1; j < 9; ++j) mass[j] = cdf[j] - cdf[j - 1];
        mass[9] = 1.0f - cdf[8];
    }

    // ---- coalesced store via LDS -----------------------------------------
#pragma unroll
    for (int j = 0; j < 10; ++j) s_out[tid * 10 + j] = mass[j];
    __syncthreads();
    const long long base = (long long)blockIdx.x * (BLOCK * 10);
#pragma unroll
    for (int r = 0; r < 10; ++r) {
        const int idx = r * BLOCK + tid;
        const long long g = base + idx;
        if (g < (long long)B * 10) out[g] = s_out[idx];
    }
}

extern "C" void kernel_launch(void* const* d_in, const int* in_sizes, int n_in,
                              void* d_out, int out_size, void* d_ws, size_t ws_size,
                              hipStream_t stream) {
    (void)n_in; (void)out_size; (void)d_ws; (void)ws_size;
    const int*   uid = (const int*)d_in[0];
    const int*   iid = (const int*)d_in[1];
    const float* uf  = (const float*)d_in[2];
    const float* vf  = (const float*)d_in[3];
    const float* ubt = (const float*)d_in[4];
    const float* ibt = (const float*)d_in[5];
    const float* uae = (const float*)d_in[6];
    const float* ube = (const float*)d_in[7];
    const float* iae = (const float*)d_in[8];
    const float* ibe = (const float*)d_in[9];
    const float* gb  = (const float*)d_in[10];
    float* out = (float*)d_out;
    const int B = in_sizes[0];
    const int grid = (B + BLOCK - 1) / BLOCK;
    hipLaunchKernelGGL(lbd_kernel, dim3(grid), dim3(BLOCK), 0, stream,
                       uid, iid, uf, vf, ubt, ibt, uae, ube, iae, ibe, gb, out, B);
}

// Round 3
// 136.103 us; speedup vs baseline: 1.0904x; 1.0904x over previous
//
#include <hip/hip_runtime.h>
#include <math.h>

#define BLOCK 256
// 16 lanes cooperate on one sample; 4 quadrature points per lane (i = m*16 + sub).

__device__ __forceinline__ float exp2_fast(float x) {
#if __has_builtin(__builtin_amdgcn_exp2f)
    return __builtin_amdgcn_exp2f(x);   // bare v_exp_f32
#else
    return __expf(x * 0.69314718055994531f);
#endif
}

__global__ __launch_bounds__(BLOCK) void lbd_kernel(
    const int* __restrict__ uid_in, const int* __restrict__ iid_in,
    const float* __restrict__ uf,  const float* __restrict__ vf,
    const float* __restrict__ ubt, const float* __restrict__ ibt,
    const float* __restrict__ uae, const float* __restrict__ ube,
    const float* __restrict__ iae, const float* __restrict__ ibe,
    const float* __restrict__ gbp, float* __restrict__ out, int B)
{
    const int tid = threadIdx.x;
    const int sub = tid & 15;                       // lane within 16-lane sample group
    const int s   = blockIdx.x * (BLOCK / 16) + (tid >> 4);
    if (s >= B) return;                             // whole group exits together

    const int u = uid_in[s];
    const int v = iid_in[s];

    // ---- coalesced feature gather: lane sub reads elements sub, sub+16, ... ----
    const long long ub = (long long)u * 65;
    const long long vb = (long long)v * 65;
    float fu0 = uf[ub + sub],      fv0 = vf[vb + sub];
    float fu1 = uf[ub + 16 + sub], fv1 = vf[vb + 16 + sub];
    float fu2 = uf[ub + 32 + sub], fv2 = vf[vb + 32 + sub];
    float fu3 = uf[ub + 48 + sub], fv3 = vf[vb + 48 + sub];

    float dotp = fu0 * fv0 + fu1 * fv1 + fu2 * fv2 + fu3 * fv3;
    float sup  = fu0 * fu0 + fu1 * fu1 + fu2 * fu2 + fu3 * fu3;
    float svp  = fv0 * fv0 + fv1 * fv1 + fv2 * fv2 + fv3 * fv3;
#pragma unroll
    for (int d = 1; d < 16; d <<= 1) {              // butterfly within 16-group
        dotp += __shfl_xor(dotp, d, 64);
        sup  += __shfl_xor(sup,  d, 64);
        svp  += __shfl_xor(svp,  d, 64);
    }

    // ---- alpha / beta (smooth; all 16 lanes redundantly) ----------------------
    const float gb = gbp[0];
    const float len_prod = sqrtf(sup) * sqrtf(svp);
    const float EPS = 1e-6f;
    const float HI  = (float)(1.0 - 1e-6);
    float mu = 0.5f + (0.5f * dotp) / fmaxf(len_prod, EPS);
    mu = fminf(fmaxf(mu, EPS), HI);
    const float ups = fmaxf(fabsf(dotp), EPS);
    const float al0 = fmaxf(0.01f, mu * ups);
    const float be0 = fmaxf(0.01f, ups - al0);
    const float alpha = fmaxf(0.01f, (gb + al0) + uae[u] + iae[v]);
    const float beta  = fmaxf(0.01f, (gb + be0) + ube[u] + ibe[v]);
    const float am1 = alpha - 1.0f;
    const float bm1 = beta  - 1.0f;

    // ---- bin-edge chain in f64 (mask-critical), data-parallel on lanes 0..9 ---
    const double STEP = 1.0 / 63.0;
    float xf_own = 0.f, lx_own = 0.f;
    int   im_own = 0;
    {
        double e = 0.0;
        if (sub < 10)
            e = exp((double)ubt[u * 10 + sub] + (double)ibt[v * 10 + sub]);
        // inclusive scan over the 16-group (lanes >=10 contribute 0)
        double c = e;
#pragma unroll
        for (int d = 1; d < 16; d <<= 1) {
            double t = __shfl_up(c, d, 16);
            if (sub >= d) c += t;
        }
        const double ssum = __shfl(c, 9, 16);       // total of 10 terms
        if (sub < 9) {
            const double x = c / ssum;              // edge x_sub (f64)
            int im = (int)(x * 63.0);
            if (im > 62) im = 62;
            while (im < 62 && (double)(im + 1) * STEP <= x) ++im;
            while (im >= 1 && (double)im * STEP > x) --im;
            im_own = im;
            xf_own = (float)x;
            lx_own = __log2f(xf_own);
        }
    }
    // broadcast per-edge data to all 16 lanes of the group
    float xfj[9], alxj[9];
    int   imj[9];
#pragma unroll
    for (int j = 0; j < 9; ++j) {
        xfj[j]  = __shfl(xf_own, j, 16);
        alxj[j] = am1 * __shfl(lx_own, j, 16);
        imj[j]  = __shfl(im_own, j, 16);
    }

    // ---- per-lane t-points (i = m*16 + sub), exact np.linspace f32 values -----
    float tfm[4], ltm[4], l1m[4];
#pragma unroll
    for (int m = 0; m < 4; ++m) {
        const int i = m * 16 + sub;
        const float tf = (float)((double)i * STEP);   // i=63 -> 1.0f exactly
        tfm[m] = tf;
        ltm[m] = __log2f(tf);                         // i=0 -> -inf (term -> 0)
        l1m[m] = __log2f(1.0f - tf);                  // i=63 -> -inf (term -> 0)
    }

    // ---- quadrature: 9 numerators + denominator, same formulation as round 2 --
    float acc[10];
#pragma unroll
    for (int j = 0; j < 10; ++j) acc[j] = 0.0f;

#pragma unroll
    for (int m = 0; m < 4; ++m) {
        const int   i    = m * 16 + sub;
        const float t    = tfm[m];
        const float altm = am1 * ltm[m];
        acc[9] += exp2_fast(fmaf(am1, ltm[m], bm1 * l1m[m]));   // denom (ends = 0)
#pragma unroll
        for (int j = 0; j < 9; ++j) {
            const float e = fmaf(bm1, __log2f(fmaf(-t, xfj[j], 1.0f)), altm + alxj[j]);
            const float y = exp2_fast(e);
            const bool ok = (unsigned)(i - 1) < (unsigned)imj[j];  // 1 <= i <= im_j
            acc[j] += ok ? y : 0.0f;
        }
    }

    // ---- reduce the 10 sums across the 16-group -------------------------------
#pragma unroll
    for (int d = 1; d < 16; d <<= 1) {
#pragma unroll
        for (int j = 0; j < 10; ++j) acc[j] += __shfl_xor(acc[j], d, 64);
    }

    // ---- epilogue: cdf -> mass; lanes 0..9 store ------------------------------
    const float dtf = (float)(1.0 / 63.0);
    const float Bab = acc[9] * dtf;
    const float rB  = 1.0f / Bab;
    float cdfv[9];
#pragma unroll
    for (int j = 0; j < 9; ++j) cdfv[j] = (acc[j] * dtf) * rB;

    float mo = cdfv[0];                               // sub == 0
#pragma unroll
    for (int j = 1; j < 9; ++j) mo = (sub == j) ? (cdfv[j] - cdfv[j - 1]) : mo;
    mo = (sub == 9) ? (1.0f - cdfv[8]) : mo;
    if (sub < 10) out[(long long)s * 10 + sub] = mo;
}

extern "C" void kernel_launch(void* const* d_in, const int* in_sizes, int n_in,
                              void* d_out, int out_size, void* d_ws, size_t ws_size,
                              hipStream_t stream) {
    (void)n_in; (void)out_size; (void)d_ws; (void)ws_size;
    const int*   uid = (const int*)d_in[0];
    const int*   iid = (const int*)d_in[1];
    const float* uf  = (const float*)d_in[2];
    const float* vf  = (const float*)d_in[3];
    const float* ubt = (const float*)d_in[4];
    const float* ibt = (const float*)d_in[5];
    const float* uae = (const float*)d_in[6];
    const float* ube = (const float*)d_in[7];
    const float* iae = (const float*)d_in[8];
    const float* ibe = (const float*)d_in[9];
    const float* gb  = (const float*)d_in[10];
    float* out = (float*)d_out;
    const int B = in_sizes[0];
    const int samples_per_block = BLOCK / 16;
    const int grid = (B + samples_per_block - 1) / samples_per_block;
    hipLaunchKernelGGL(lbd_kernel, dim3(grid), dim3(BLOCK), 0, stream,
                       uid, iid, uf, vf, ubt, ibt, uae, ube, iae, ibe, gb, out, B);
}